// Round 1
// baseline (509.208 us; speedup 1.0000x reference)
//
#include <hip/hip_runtime.h>

#define GN 512  // N hard-coded per reference

// g[b,i,j] = cos(phi_i + phi_j) = c_i*c_j - s_i*s_j
// c = clamp(minmax_scale(x), -1+eps, 1-eps), s = sqrt(1-c^2)  (phi in [0,pi])
__global__ __launch_bounds__(256) void gram_kernel(const float* __restrict__ x,
                                                   float* __restrict__ out) {
    __shared__ float sc[GN];
    __shared__ float ss[GN];
    __shared__ float wmin[4], wmax[4];

    const int b    = blockIdx.x;   // batch
    const int part = blockIdx.y;   // 0..3, quarter of the output tile
    const int t    = threadIdx.x;  // 0..255

    // ---- Phase 1: per-batch min/max + c,s into LDS (2 elems per thread) ----
    const float* xb = x + (size_t)b * GN;
    float2 v = ((const float2*)xb)[t];

    float lmin = fminf(v.x, v.y);
    float lmax = fmaxf(v.x, v.y);
    #pragma unroll
    for (int off = 32; off > 0; off >>= 1) {
        lmin = fminf(lmin, __shfl_down(lmin, off));
        lmax = fmaxf(lmax, __shfl_down(lmax, off));
    }
    const int wave = t >> 6;
    if ((t & 63) == 0) { wmin[wave] = lmin; wmax[wave] = lmax; }
    __syncthreads();
    const float mn  = fminf(fminf(wmin[0], wmin[1]), fminf(wmin[2], wmin[3]));
    const float mx  = fmaxf(fmaxf(wmax[0], wmax[1]), fmaxf(wmax[2], wmax[3]));
    const float inv = 1.0f / (mx - mn);
    const float eps = 1e-6f;
    const float lo  = -1.0f + eps, hi = 1.0f - eps;

    float c0 = fminf(fmaxf((2.0f * v.x - mx - mn) * inv, lo), hi);
    float c1 = fminf(fmaxf((2.0f * v.y - mx - mn) * inv, lo), hi);
    sc[2 * t]     = c0;
    sc[2 * t + 1] = c1;
    ss[2 * t]     = sqrtf(fmaxf(1.0f - c0 * c0, 0.0f));
    ss[2 * t + 1] = sqrtf(fmaxf(1.0f - c1 * c1, 0.0f));
    __syncthreads();

    // ---- Phase 2: write this block's quarter of the 512x512 tile ----
    // 65536 float4 per batch; this block does 16384 (64 iters x 256 lanes).
    float4* ob = (float4*)(out + (size_t)b * GN * GN);
    const int base = part * 16384;
    #pragma unroll 4
    for (int k = 0; k < 64; ++k) {
        int f  = base + k * 256 + t;  // float4 index in the batch tile
        int i  = f >> 7;              // row (wave-uniform: 128 lanes share it)
        int j4 = (f & 127) << 2;      // column base

        float  ci = sc[i],  si = ss[i];           // LDS broadcast
        float4 cj = *(const float4*)&sc[j4];      // stride-1 ds_read_b128
        float4 sj = *(const float4*)&ss[j4];

        float4 g;
        g.x = fmaf(ci, cj.x, -si * sj.x);
        g.y = fmaf(ci, cj.y, -si * sj.y);
        g.z = fmaf(ci, cj.z, -si * sj.z);
        g.w = fmaf(ci, cj.w, -si * sj.w);
        ob[f] = g;  // coalesced global_store_dwordx4
    }
}

extern "C" void kernel_launch(void* const* d_in, const int* in_sizes, int n_in,
                              void* d_out, int out_size, void* d_ws, size_t ws_size,
                              hipStream_t stream) {
    const float* x = (const float*)d_in[0];
    float* out = (float*)d_out;
    dim3 grid(512, 4);  // 512 batches x 4 output quarters = 2048 blocks
    gram_kernel<<<grid, 256, 0, stream>>>(x, out);
}